// Round 13
// baseline (101.839 us; speedup 1.0000x reference)
//
#include <hip/hip_runtime.h>
#include <stdint.h>

// hipcc defaults to -ffp-contract=fast; FMA fusion perturbs IoU by ~1 ulp vs
// numpy and flips discrete selections (R3-R6 ladder). Force per-op IEEE f32.
#pragma clang fp contract(off)

#define BATCH 32
#define NROI  12000
#define NGT   200
#define BGCLS 20
#define ROIBS 256
#define NPOS  64
#define NBIN  1024
#define CAP   2048
#define TSEL  1024       // k_sel block size
#define VPT2  12         // ceil(NROI/TSEL) values per k_sel thread
#define HSH   16         // histogram shards (lane-based)
#define HST   (NBIN + 2) // shard stride: same bin -> different banks/addresses
#define DELTA 1e-6f      // approx error window (~8x the rcp+mul error bound)

// Exact reference IoU max/argmax over compacted valid GTs (first-max wins).
// Bit-exact numpy f32: left-to-right ((ar+ag)-inter)+1e-8, IEEE div.
__device__ __forceinline__ void roi_maxiou_all(const float4* cbox, const float* carea,
                                               int nv, float ry1, float rx1,
                                               float ry2, float rx2,
                                               float& best, int& bj) {
#pragma clang fp contract(off)
  float ar = (ry2 - ry1) * (rx2 - rx1);
  best = -1.0f; bj = 0;
  for (int j = 0; j < nv; ++j) {
    float4 q = cbox[j];
    float yy1 = fmaxf(ry1, q.x);
    float xx1 = fmaxf(rx1, q.y);
    float yy2 = fminf(ry2, q.z);
    float xx2 = fminf(rx2, q.w);
    float inter = fmaxf(yy2 - yy1, 0.0f) * fmaxf(xx2 - xx1, 0.0f);
    float den = ((ar + carea[j]) - inter) + 1e-8f;
    float iou = inter / den;
    if (iou > best) { best = iou; bj = j; }      // strict > == first-index argmax
  }
}

// Approx max-IoU (guidance only): rcp instead of IEEE div, no argmax.
// inter/den identical to exact; only div is approximated:
// |approx-exact| <= ~2 ulp rel (~1.2e-7 abs at 0.5) << DELTA.
__device__ __forceinline__ float approx_max(const float4* cbox, const float* carea,
                                            int nv, float4 r) {
  float ar = (r.z - r.x) * (r.w - r.y);
  float va = -1.0f, vb = -1.0f;
#pragma unroll 4
  for (int j = 0; j < nv; ++j) {
    float4 q = cbox[j];
    float yy1 = fmaxf(r.x, q.x);
    float xx1 = fmaxf(r.y, q.y);
    float yy2 = fminf(r.z, q.z);
    float xx2 = fminf(r.w, q.w);
    float inter = fmaxf(yy2 - yy1, 0.0f) * fmaxf(xx2 - xx1, 0.0f);
    float den = ((ar + carea[j]) - inter) + 1e-8f;
    float a = inter * __builtin_amdgcn_rcpf(den);
    if (j & 1) vb = fmaxf(vb, a); else va = fmaxf(va, a);
  }
  return fmaxf(va, vb);
}

// Approx-only pass: uniform duration, no divergence, minimal ops.
__global__ __launch_bounds__(256) void k_ioumax(const float* __restrict__ rois,
                                                const int* __restrict__ gtc,
                                                const float* __restrict__ gtb,
                                                float* __restrict__ max_iou) {
  __shared__ float4 cbox[NGT];
  __shared__ float carea[NGT];
  __shared__ int snv, wtmp[4];
  const int b = blockIdx.y;
  const int tid = threadIdx.x;

  {                                              // order-preserving compaction
    bool valid = false; float4 p = make_float4(0.f, 0.f, 0.f, 0.f);
    if (tid < NGT) {
      p = *(const float4*)(gtb + ((size_t)b * NGT + tid) * 4);
      valid = gtc[(size_t)b * NGT + tid] < BGCLS;
    }
    unsigned long long m = __ballot(valid);
    int w = tid >> 6;
    if ((tid & 63) == 0) wtmp[w] = __popcll(m);
    __syncthreads();
    if (tid == 0) snv = wtmp[0] + wtmp[1] + wtmp[2] + wtmp[3];
    if (valid) {
      int off = 0;
      for (int i = 0; i < w; ++i) off += wtmp[i];
      int pos = off + __popcll(m & ((1ull << (tid & 63)) - 1ull));
      cbox[pos] = p;
      carea[pos] = (p.z - p.x) * (p.w - p.y);
    }
    __syncthreads();
  }
  int n = blockIdx.x * 256 + tid;
  if (n >= NROI) return;
  const float4 r = *(const float4*)(rois + ((size_t)b * NROI + n) * 4);
  max_iou[(size_t)b * NROI + n] = approx_max(cbox, carea, snv, r);
}

// One 1024-thread block per image. BOTH phases histogram-prune on approx
// values (bounded candidate sets << CAP -- R12's bug was unbounded pos
// candidates overflowing CAP), then EXACT 190-GT eval per candidate; ranks,
// ties, labels, deltas all from exact keys -> output bit-identical to R6.
// Superset proof (per phase): suffix(T) >= need+X with <=X fakes => >= need
// true entries at approx-bin >= T => exact top-need at exact-bin >= T-1 =>
// approx-bin >= T-2 = Tc. key = bits<<32|(0x7fffffff-n): desc == (val desc,
// idx asc) == jax stable top_k; +2.0 rounding tie-collapse preserved.
template <bool USE_WS>
__global__ __launch_bounds__(TSEL) void k_sel(const float* __restrict__ rois,
                                              const int* __restrict__ gtc,
                                              const float* __restrict__ gtb,
                                              const float* __restrict__ max_iou,
                                              float* __restrict__ out) {
#pragma clang fp contract(off)
  __shared__ float4 cbox[NGT];
  __shared__ float carea[NGT];
  __shared__ int ccls[NGT];
  __shared__ int snv, wtmp[16];
  __shared__ int wtot[16], wnext[16];
  __shared__ int plist[CAP];
  __shared__ unsigned long long keyl[CAP];
  __shared__ int bjl[CAP];
  __shared__ int hs[HSH][HST];
  __shared__ int ss[NBIN];
  __shared__ int sel_r[ROIBS];
  __shared__ int sel_b[ROIBS];
  __shared__ int scnt, sX, sT, sPos;
  const int b = blockIdx.x;
  const int tid = threadIdx.x;
  const int lane = tid & 63;

  {                                              // order-preserving compaction
    bool valid = false; float4 p = make_float4(0.f, 0.f, 0.f, 0.f); int cls = BGCLS;
    if (tid < NGT) {
      p = *(const float4*)(gtb + ((size_t)b * NGT + tid) * 4);
      cls = gtc[(size_t)b * NGT + tid];
      valid = (cls < BGCLS);
    }
    unsigned long long m = __ballot(valid);
    int w = tid >> 6;
    if ((tid & 63) == 0) wtmp[w] = __popcll(m);
    if (tid < ROIBS) { sel_r[tid] = 0; sel_b[tid] = 0; }
    __syncthreads();
    if (tid == 0) { int s = 0; for (int i = 0; i < 16; ++i) s += wtmp[i]; snv = s; }
    if (valid) {
      int off = 0;
      for (int i = 0; i < w; ++i) off += wtmp[i];
      int pos = off + __popcll(m & ((1ull << (tid & 63)) - 1ull));
      cbox[pos] = p;
      carea[pos] = (p.z - p.x) * (p.w - p.y);
      ccls[pos] = cls;
    }
    __syncthreads();
  }
  const int nv = snv;

  // ---- register-resident approx values: n = tid + i*1024 ----
  float v[VPT2];
#pragma unroll
  for (int i = 0; i < VPT2; ++i) {
    int n = tid + (i << 10);
    if (n < NROI) {
      if constexpr (USE_WS) {
        v[i] = max_iou[(size_t)b * NROI + n];
      } else {
        const float4 r = *(const float4*)(rois + ((size_t)b * NROI + n) * 4);
        v[i] = approx_max(cbox, carea, nv, r);
      }
    } else v[i] = -3.0f;
  }

  // signed-clamped bin (guards underflow for values just below the base)
  auto mkbin = [](unsigned kh, unsigned base, int shift) -> int {
    int bin = ((int)(kh - base)) >> shift;       // arithmetic shift
    return max(min(bin, NBIN - 1), 0);
  };

  // threshold bin: highest T with suffix(T) >= needv (0 if total < needv)
  auto find_T = [&](int needv) -> int {
    if (tid == 0) sT = 0;
    __syncthreads();
    int cnt_bin = 0;
#pragma unroll
    for (int i = 0; i < HSH; ++i) cnt_bin += hs[i][tid];
    const int w = tid >> 6;
    int sfx = cnt_bin;                           // wave suffix scan (bins desc)
#pragma unroll
    for (int off = 1; off < 64; off <<= 1) {
      int t = __shfl_down(sfx, off, 64);
      sfx += (lane + off < 64) ? t : 0;
    }
    if (lane == 0) wtot[w] = sfx;
    __syncthreads();
    if (tid < 16) {
      int s = 0;
      for (int i = tid + 1; i < 16; ++i) s += wtot[i];
      wnext[tid] = s;
    }
    __syncthreads();
    const int suffix = sfx + wnext[w];           // total over bins >= tid
    ss[tid] = suffix;
    __syncthreads();
    int nxt = (tid + 1 < NBIN) ? ss[tid + 1] : 0;
    if (suffix >= needv && nxt < needv) sT = tid;
    __syncthreads();
    return sT;
  };

  const int sh = tid & (HSH - 1);                // lane-sharded histogram

  // ===== positive phase: approx >= 0.5-DELTA, bins over [0.5, 1.0) =====
  for (int i = tid; i < HSH * HST; i += TSEL) ((int*)hs)[i] = 0;
  if (tid == 0) { scnt = 0; sX = 0; sPos = 0; }
  __syncthreads();
#pragma unroll
  for (int i = 0; i < VPT2; ++i) {
    int n = tid + (i << 10);
    float x = v[i];
    bool inb = (n < NROI) && (x >= 0.5f - DELTA);
    if (inb) atomicAdd(&hs[sh][mkbin(__float_as_uint(x), 0x3F000000u, 13)], 1);
    bool bnd = inb && (x < 0.5f + DELTA);        // ambiguous boundary window
    unsigned long long mx = __ballot(bnd);
    if (lane == 0 && mx) atomicAdd(&sX, __popcll(mx));
  }
  __syncthreads();
  const int XB = sX;                             // bounds fakes, both phases
  const int Tp = max(find_T(NPOS + XB) - 2, 0);
#pragma unroll
  for (int i = 0; i < VPT2; ++i) {               // ballot-compact candidates
    int n = tid + (i << 10);
    float x = v[i];
    bool pred = (n < NROI) && (x >= 0.5f - DELTA) &&
                (mkbin(__float_as_uint(x), 0x3F000000u, 13) >= Tp);
    unsigned long long mk = __ballot(pred);
    int c = __popcll(mk);
    int bs = 0;
    if (lane == 0 && c) bs = atomicAdd(&scnt, c);
    bs = __shfl(bs, 0, 64);
    if (pred) {
      int idx = bs + __popcll(mk & ((1ull << lane) - 1ull));
      if (idx < CAP) plist[idx] = n;
    }
  }
  __syncthreads();
  const int cntp = min(scnt, CAP);
  for (int i = tid; i < cntp; i += TSEL) {       // exact eval of candidates
    int n = plist[i];
    const float4 r = *(const float4*)(rois + ((size_t)b * NROI + n) * 4);
    float best; int bj;
    roi_maxiou_all(cbox, carea, nv, r.x, r.y, r.z, r.w, best, bj);
    bool ok = (best >= 0.5f);                    // exact classification
    keyl[i] = ok ? (((unsigned long long)__float_as_uint(best) << 32)
                   | (unsigned)(0x7fffffff - n)) : 0ull;
    bjl[i] = bj;
    if (ok) atomicAdd(&sPos, 1);
  }
  __syncthreads();
  const int P = min(sPos, NPOS);
  for (int i = tid; i < cntp; i += TSEL) {       // rank selection, keys unique
    unsigned long long ki = keyl[i];
    if (ki) {
      int rank = 0;
      for (int j = 0; j < cntp; ++j) rank += (keyl[j] > ki);
      if (rank < P) {
        sel_r[rank] = 0x7fffffff - (int)(ki & 0xffffffffu);
        sel_b[rank] = bjl[i];
      }
    }
  }
  __syncthreads();

  // ===== negative phase: approx < 0.5+DELTA, bins on bits(x+2) [2.0,2.5) ===
  const int need = ROIBS - P;
  for (int i = tid; i < HSH * HST; i += TSEL) ((int*)hs)[i] = 0;
  if (tid == 0) scnt = 0;
  __syncthreads();
#pragma unroll
  for (int i = 0; i < VPT2; ++i) {
    int n = tid + (i << 10);
    float x = v[i];
    if (n < NROI && x < 0.5f + DELTA)
      atomicAdd(&hs[sh][mkbin(__float_as_uint(x + 2.0f), 0x40000000u, 11)], 1);
  }
  __syncthreads();
  const int Tn = max(find_T(need + XB) - 2, 0);
#pragma unroll
  for (int i = 0; i < VPT2; ++i) {               // ballot-compact candidates
    int n = tid + (i << 10);
    float x = v[i];
    bool pred = (n < NROI) && (x < 0.5f + DELTA) &&
                (mkbin(__float_as_uint(x + 2.0f), 0x40000000u, 11) >= Tn);
    unsigned long long mk = __ballot(pred);
    int c = __popcll(mk);
    int bs = 0;
    if (lane == 0 && c) bs = atomicAdd(&scnt, c);
    bs = __shfl(bs, 0, 64);
    if (pred) {
      int idx = bs + __popcll(mk & ((1ull << lane) - 1ull));
      if (idx < CAP) plist[idx] = n;
    }
  }
  __syncthreads();
  const int cntn = min(scnt, CAP);
  for (int i = tid; i < cntn; i += TSEL) {       // exact eval of candidates
    int n = plist[i];
    const float4 r = *(const float4*)(rois + ((size_t)b * NROI + n) * 4);
    float best; int bj;
    roi_maxiou_all(cbox, carea, nv, r.x, r.y, r.z, r.w, best, bj);
    bool ok = (best < 0.5f);                     // exact classification
    // exact neg key: f32(v+2.0) -- the +2.0 ROUNDING merges nearby ious,
    // merged ties break asc-index via the low word.
    keyl[i] = ok ? (((unsigned long long)__float_as_uint(best + 2.0f) << 32)
                   | (unsigned)(0x7fffffff - n)) : 0ull;
    bjl[i] = bj;
  }
  __syncthreads();
  for (int i = tid; i < cntn; i += TSEL) {       // rank selection
    unsigned long long ki = keyl[i];
    if (ki) {
      int rank = 0;
      for (int j = 0; j < cntn; ++j) rank += (keyl[j] > ki);
      if (rank < need) {
        sel_r[P + rank] = 0x7fffffff - (int)(ki & 0xffffffffu);
        sel_b[P + rank] = bjl[i];
      }
    }
  }
  __syncthreads();

  // ===== emit (f32 output): 4 threads per slot; covers all of d_out =====
  {
    const int slot = tid >> 2, q = tid & 3;
    const int r = sel_r[slot];
    const int bj = sel_b[slot];
    const int isp = (slot < P) ? 1 : 0;
    const float4 rv = *(const float4*)(rois + ((size_t)b * NROI + r) * 4);
    float ry1 = rv.x, rx1 = rv.y, ry2 = rv.z, rx2 = rv.w;
    int label = isp ? ccls[bj] : BGCLS;

    float* out1 = out;                                    // [B,256,4]
    float* out2 = out + (size_t)BATCH * ROIBS * 4;        // [B,256,21]
    float* out3 = out + (size_t)BATCH * ROIBS * 25;       // [B,256,160]
    size_t row = (size_t)b * ROIBS + slot;

    if (q == 0) {
      *(float4*)(out1 + row * 4) = rv;                    // bit-exact roi copy
      float* o2 = out2 + row * 21;
      for (int c = 0; c <= BGCLS; ++c) o2[c] = (c == label) ? 1.0f : 0.0f;
    }

    float t0 = 0.f, t1 = 0.f, t2 = 0.f, t3 = 0.f;
    if (isp) {
      const float eps = 1e-6f;
      float4 g = cbox[bj];
      float gy1 = g.x, gx1 = g.y, gy2 = g.z, gx2 = g.w;
      float rh = ry2 - ry1, rw = rx2 - rx1;
      float rcy = ry1 + rh * 0.5f, rcx = rx1 + rw * 0.5f;
      float gh = gy2 - gy1, gw = gx2 - gx1;
      float gcy = gy1 + gh * 0.5f, gcx = gx1 + gw * 0.5f;
      t0 = ((gcx - rcx) / (rw + eps)) * 10.0f;
      t1 = ((gcy - rcy) / (rh + eps)) * 10.0f;
      t2 = logf(fmaxf(gw, eps) / (rw + eps)) * 5.0f;
      t3 = logf(fmaxf(gh, eps) / (rh + eps)) * 5.0f;
    }
    int m0 = label * 4;                          // meaningful only when isp
    float* o3 = out3 + row * 160;
    for (int c = q * 10; c < q * 10 + 10; ++c) { // 10 x 16B stores per thread
      float4 wv = make_float4(0.f, 0.f, 0.f, 0.f);
      if (isp) {
        float* wp = &wv.x;
#pragma unroll
        for (int jj = 0; jj < 4; ++jj) {
          int e = c * 4 + jj;
          float x = 0.f;
          if (e >= m0 && e < m0 + 4) x = 1.0f;   // mask4 half [0,80)
          int d = e - 80 - m0;                   // deltas half [80,160)
          if (d == 0) x = t0; else if (d == 1) x = t1;
          else if (d == 2) x = t2; else if (d == 3) x = t3;
          wp[jj] = x;
        }
      }
      *(float4*)(o3 + c * 4) = wv;
    }
  }
}

extern "C" void kernel_launch(void* const* d_in, const int* in_sizes, int n_in,
                              void* d_out, int out_size, void* d_ws, size_t ws_size,
                              hipStream_t stream) {
  const float* rois = (const float*)d_in[0];   // [32,12000,4] f32
  const int*   gtc  = (const int*)d_in[1];     // [32,200] i32
  const float* gtb  = (const float*)d_in[2];   // [32,200,4] f32
  float*       out  = (float*)d_out;           // f32, 32*256*185 elements

  size_t need = (size_t)BATCH * NROI * sizeof(float);   // approx max_iou only
  if (d_ws && ws_size >= need) {
    float* mi = (float*)d_ws;
    k_ioumax<<<dim3((NROI + 255) / 256, BATCH), 256, 0, stream>>>(rois, gtc, gtb, mi);
    k_sel<true><<<BATCH, TSEL, 0, stream>>>(rois, gtc, gtb, mi, out);
  } else {
    k_sel<false><<<BATCH, TSEL, 0, stream>>>(rois, gtc, gtb, nullptr, out);
  }
}

// Round 14
// 98.681 us; speedup vs baseline: 1.0320x; 1.0320x over previous
//
#include <hip/hip_runtime.h>
#include <stdint.h>

// hipcc defaults to -ffp-contract=fast; FMA fusion perturbs IoU by ~1 ulp vs
// numpy and flips discrete selections (R3-R6 ladder). Force per-op IEEE f32.
#pragma clang fp contract(off)

#define BATCH 32
#define NROI  12000
#define NGT   200
#define BGCLS 20
#define ROIBS 256
#define NPOS  64
#define NBIN  1024
#define CAP   2048
#define TSEL  1024       // k_sel block size
#define VPT2  12         // ceil(NROI/TSEL) values per k_sel thread
#define HSH   16         // histogram shards (lane-based)
#define HST   (NBIN + 2) // shard stride: same bin -> different banks/addresses
#define DELTA 1e-6f      // approx error window (~8x the rcp+mul error bound)

// Exact reference IoU max/argmax over compacted valid GTs (first-max wins).
// Bit-exact numpy f32: left-to-right ((ar+ag)-inter)+1e-8, IEEE div.
// unroll 4: loads/arith of 4 iterations overlap (latency fix, R13 post-mortem);
// the best/bj compare chain keeps program order -> bit-exact.
__device__ __forceinline__ void roi_maxiou_all(const float4* cbox, const float* carea,
                                               int nv, float ry1, float rx1,
                                               float ry2, float rx2,
                                               float& best, int& bj) {
#pragma clang fp contract(off)
  float ar = (ry2 - ry1) * (rx2 - rx1);
  best = -1.0f; bj = 0;
#pragma unroll 4
  for (int j = 0; j < nv; ++j) {
    float4 q = cbox[j];
    float yy1 = fmaxf(ry1, q.x);
    float xx1 = fmaxf(rx1, q.y);
    float yy2 = fminf(ry2, q.z);
    float xx2 = fminf(rx2, q.w);
    float inter = fmaxf(yy2 - yy1, 0.0f) * fmaxf(xx2 - xx1, 0.0f);
    float den = ((ar + carea[j]) - inter) + 1e-8f;
    float iou = inter / den;
    if (iou > best) { best = iou; bj = j; }      // strict > == first-index argmax
  }
}

// Approx max-IoU (guidance only): rcp instead of IEEE div, no argmax.
// inter/den identical to exact; only div is approximated:
// |approx-exact| <= ~2 ulp rel (~1.2e-7 abs at 0.5) << DELTA.
__device__ __forceinline__ float approx_max(const float4* cbox, const float* carea,
                                            int nv, float4 r) {
  float ar = (r.z - r.x) * (r.w - r.y);
  float va = -1.0f, vb = -1.0f;
#pragma unroll 4
  for (int j = 0; j < nv; ++j) {
    float4 q = cbox[j];
    float yy1 = fmaxf(r.x, q.x);
    float xx1 = fmaxf(r.y, q.y);
    float yy2 = fminf(r.z, q.z);
    float xx2 = fminf(r.w, q.w);
    float inter = fmaxf(yy2 - yy1, 0.0f) * fmaxf(xx2 - xx1, 0.0f);
    float den = ((ar + carea[j]) - inter) + 1e-8f;
    float a = inter * __builtin_amdgcn_rcpf(den);
    if (j & 1) vb = fmaxf(vb, a); else va = fmaxf(va, a);
  }
  return fmaxf(va, vb);
}

// Approx-only pass: uniform duration, no divergence, minimal ops.
__global__ __launch_bounds__(256) void k_ioumax(const float* __restrict__ rois,
                                                const int* __restrict__ gtc,
                                                const float* __restrict__ gtb,
                                                float* __restrict__ max_iou) {
  __shared__ float4 cbox[NGT];
  __shared__ float carea[NGT];
  __shared__ int snv, wtmp[4];
  const int b = blockIdx.y;
  const int tid = threadIdx.x;

  {                                              // order-preserving compaction
    bool valid = false; float4 p = make_float4(0.f, 0.f, 0.f, 0.f);
    if (tid < NGT) {
      p = *(const float4*)(gtb + ((size_t)b * NGT + tid) * 4);
      valid = gtc[(size_t)b * NGT + tid] < BGCLS;
    }
    unsigned long long m = __ballot(valid);
    int w = tid >> 6;
    if ((tid & 63) == 0) wtmp[w] = __popcll(m);
    __syncthreads();
    if (tid == 0) snv = wtmp[0] + wtmp[1] + wtmp[2] + wtmp[3];
    if (valid) {
      int off = 0;
      for (int i = 0; i < w; ++i) off += wtmp[i];
      int pos = off + __popcll(m & ((1ull << (tid & 63)) - 1ull));
      cbox[pos] = p;
      carea[pos] = (p.z - p.x) * (p.w - p.y);
    }
    __syncthreads();
  }
  int n = blockIdx.x * 256 + tid;
  if (n >= NROI) return;
  const float4 r = *(const float4*)(rois + ((size_t)b * NROI + n) * 4);
  max_iou[(size_t)b * NROI + n] = approx_max(cbox, carea, snv, r);
}

// One 1024-thread block per image. BOTH phases histogram-prune on approx
// values (bounded candidate sets << CAP), then EXACT 190-GT eval per
// candidate; ranks, ties, labels, deltas all from exact keys -> output
// bit-identical to R6. Superset proof (per phase): suffix(T) >= need+X with
// <=X fakes => >= need true entries at approx-bin >= T => exact top-need at
// exact-bin >= T-1 => approx-bin >= T-2 = Tc. key = bits<<32|(0x7fffffff-n):
// desc == (val desc, idx asc) == jax stable top_k; +2.0 rounding tie-collapse
// preserved.
template <bool USE_WS>
__global__ __launch_bounds__(TSEL) void k_sel(const float* __restrict__ rois,
                                              const int* __restrict__ gtc,
                                              const float* __restrict__ gtb,
                                              const float* __restrict__ max_iou,
                                              float* __restrict__ out) {
#pragma clang fp contract(off)
  __shared__ float4 cbox[NGT];
  __shared__ float carea[NGT];
  __shared__ int ccls[NGT];
  __shared__ int snv, wtmp[16];
  __shared__ int wtot[16], wnext[16];
  __shared__ int plist[CAP];
  __shared__ unsigned long long keyl[CAP];
  __shared__ int bjl[CAP];
  __shared__ int hs[HSH][HST];
  __shared__ int ss[NBIN];
  __shared__ int sel_r[ROIBS];
  __shared__ int sel_b[ROIBS];
  __shared__ int scnt, sX, sT, sPos;
  const int b = blockIdx.x;
  const int tid = threadIdx.x;
  const int lane = tid & 63;

  {                                              // order-preserving compaction
    bool valid = false; float4 p = make_float4(0.f, 0.f, 0.f, 0.f); int cls = BGCLS;
    if (tid < NGT) {
      p = *(const float4*)(gtb + ((size_t)b * NGT + tid) * 4);
      cls = gtc[(size_t)b * NGT + tid];
      valid = (cls < BGCLS);
    }
    unsigned long long m = __ballot(valid);
    int w = tid >> 6;
    if ((tid & 63) == 0) wtmp[w] = __popcll(m);
    if (tid < ROIBS) { sel_r[tid] = 0; sel_b[tid] = 0; }
    __syncthreads();
    if (tid == 0) { int s = 0; for (int i = 0; i < 16; ++i) s += wtmp[i]; snv = s; }
    if (valid) {
      int off = 0;
      for (int i = 0; i < w; ++i) off += wtmp[i];
      int pos = off + __popcll(m & ((1ull << (tid & 63)) - 1ull));
      cbox[pos] = p;
      carea[pos] = (p.z - p.x) * (p.w - p.y);
      ccls[pos] = cls;
    }
    __syncthreads();
  }
  const int nv = snv;

  // ---- register-resident approx values: n = tid + i*1024 ----
  float v[VPT2];
#pragma unroll
  for (int i = 0; i < VPT2; ++i) {
    int n = tid + (i << 10);
    if (n < NROI) {
      if constexpr (USE_WS) {
        v[i] = max_iou[(size_t)b * NROI + n];
      } else {
        const float4 r = *(const float4*)(rois + ((size_t)b * NROI + n) * 4);
        v[i] = approx_max(cbox, carea, nv, r);
      }
    } else v[i] = -3.0f;
  }

  // signed-clamped bin (guards underflow for values just below the base)
  auto mkbin = [](unsigned kh, unsigned base, int shift) -> int {
    int bin = ((int)(kh - base)) >> shift;       // arithmetic shift
    return max(min(bin, NBIN - 1), 0);
  };

  // threshold bin: highest T with suffix(T) >= needv (0 if total < needv)
  auto find_T = [&](int needv) -> int {
    if (tid == 0) sT = 0;
    __syncthreads();
    int cnt_bin = 0;
#pragma unroll
    for (int i = 0; i < HSH; ++i) cnt_bin += hs[i][tid];
    const int w = tid >> 6;
    int sfx = cnt_bin;                           // wave suffix scan (bins desc)
#pragma unroll
    for (int off = 1; off < 64; off <<= 1) {
      int t = __shfl_down(sfx, off, 64);
      sfx += (lane + off < 64) ? t : 0;
    }
    if (lane == 0) wtot[w] = sfx;
    __syncthreads();
    if (tid < 16) {
      int s = 0;
      for (int i = tid + 1; i < 16; ++i) s += wtot[i];
      wnext[tid] = s;
    }
    __syncthreads();
    const int suffix = sfx + wnext[w];           // total over bins >= tid
    ss[tid] = suffix;
    __syncthreads();
    int nxt = (tid + 1 < NBIN) ? ss[tid + 1] : 0;
    if (suffix >= needv && nxt < needv) sT = tid;
    __syncthreads();
    return sT;
  };

  // rank = #{keys > ki} over keyl[0..cnt): 4 independent accumulators
  // (order-independent sum; unroll pipelines the broadcast LDS reads).
  auto rank_of = [&](unsigned long long ki, int cnt) -> int {
    int r0 = 0, r1 = 0, r2 = 0, r3 = 0;
    int j = 0;
    for (; j + 4 <= cnt; j += 4) {
      r0 += (keyl[j + 0] > ki);
      r1 += (keyl[j + 1] > ki);
      r2 += (keyl[j + 2] > ki);
      r3 += (keyl[j + 3] > ki);
    }
    for (; j < cnt; ++j) r0 += (keyl[j] > ki);
    return r0 + r1 + r2 + r3;
  };

  const int sh = tid & (HSH - 1);                // lane-sharded histogram

  // ===== positive phase: approx >= 0.5-DELTA, bins over [0.5, 1.0) =====
  for (int i = tid; i < HSH * HST; i += TSEL) ((int*)hs)[i] = 0;
  if (tid == 0) { scnt = 0; sX = 0; sPos = 0; }
  __syncthreads();
#pragma unroll
  for (int i = 0; i < VPT2; ++i) {
    int n = tid + (i << 10);
    float x = v[i];
    bool inb = (n < NROI) && (x >= 0.5f - DELTA);
    if (inb) atomicAdd(&hs[sh][mkbin(__float_as_uint(x), 0x3F000000u, 13)], 1);
    bool bnd = inb && (x < 0.5f + DELTA);        // ambiguous boundary window
    unsigned long long mx = __ballot(bnd);
    if (lane == 0 && mx) atomicAdd(&sX, __popcll(mx));
  }
  __syncthreads();
  const int XB = sX;                             // bounds fakes, both phases
  const int Tp = max(find_T(NPOS + XB) - 2, 0);
#pragma unroll
  for (int i = 0; i < VPT2; ++i) {               // ballot-compact candidates
    int n = tid + (i << 10);
    float x = v[i];
    bool pred = (n < NROI) && (x >= 0.5f - DELTA) &&
                (mkbin(__float_as_uint(x), 0x3F000000u, 13) >= Tp);
    unsigned long long mk = __ballot(pred);
    int c = __popcll(mk);
    int bs = 0;
    if (lane == 0 && c) bs = atomicAdd(&scnt, c);
    bs = __shfl(bs, 0, 64);
    if (pred) {
      int idx = bs + __popcll(mk & ((1ull << lane) - 1ull));
      if (idx < CAP) plist[idx] = n;
    }
  }
  __syncthreads();
  const int cntp = min(scnt, CAP);
  for (int i = tid; i < cntp; i += TSEL) {       // exact eval of candidates
    int n = plist[i];
    const float4 r = *(const float4*)(rois + ((size_t)b * NROI + n) * 4);
    float best; int bj;
    roi_maxiou_all(cbox, carea, nv, r.x, r.y, r.z, r.w, best, bj);
    bool ok = (best >= 0.5f);                    // exact classification
    keyl[i] = ok ? (((unsigned long long)__float_as_uint(best) << 32)
                   | (unsigned)(0x7fffffff - n)) : 0ull;
    bjl[i] = bj;
    if (ok) atomicAdd(&sPos, 1);
  }
  __syncthreads();
  const int P = min(sPos, NPOS);
  for (int i = tid; i < cntp; i += TSEL) {       // rank selection, keys unique
    unsigned long long ki = keyl[i];
    if (ki) {
      int rank = rank_of(ki, cntp);
      if (rank < P) {
        sel_r[rank] = 0x7fffffff - (int)(ki & 0xffffffffu);
        sel_b[rank] = bjl[i];
      }
    }
  }
  __syncthreads();

  // ===== negative phase: approx < 0.5+DELTA, bins on bits(x+2) [2.0,2.5) ===
  const int need = ROIBS - P;
  for (int i = tid; i < HSH * HST; i += TSEL) ((int*)hs)[i] = 0;
  if (tid == 0) scnt = 0;
  __syncthreads();
#pragma unroll
  for (int i = 0; i < VPT2; ++i) {
    int n = tid + (i << 10);
    float x = v[i];
    if (n < NROI && x < 0.5f + DELTA)
      atomicAdd(&hs[sh][mkbin(__float_as_uint(x + 2.0f), 0x40000000u, 11)], 1);
  }
  __syncthreads();
  const int Tn = max(find_T(need + XB) - 2, 0);
#pragma unroll
  for (int i = 0; i < VPT2; ++i) {               // ballot-compact candidates
    int n = tid + (i << 10);
    float x = v[i];
    bool pred = (n < NROI) && (x < 0.5f + DELTA) &&
                (mkbin(__float_as_uint(x + 2.0f), 0x40000000u, 11) >= Tn);
    unsigned long long mk = __ballot(pred);
    int c = __popcll(mk);
    int bs = 0;
    if (lane == 0 && c) bs = atomicAdd(&scnt, c);
    bs = __shfl(bs, 0, 64);
    if (pred) {
      int idx = bs + __popcll(mk & ((1ull << lane) - 1ull));
      if (idx < CAP) plist[idx] = n;
    }
  }
  __syncthreads();
  const int cntn = min(scnt, CAP);
  for (int i = tid; i < cntn; i += TSEL) {       // exact eval of candidates
    int n = plist[i];
    const float4 r = *(const float4*)(rois + ((size_t)b * NROI + n) * 4);
    float best; int bj;
    roi_maxiou_all(cbox, carea, nv, r.x, r.y, r.z, r.w, best, bj);
    bool ok = (best < 0.5f);                     // exact classification
    // exact neg key: f32(v+2.0) -- the +2.0 ROUNDING merges nearby ious,
    // merged ties break asc-index via the low word.
    keyl[i] = ok ? (((unsigned long long)__float_as_uint(best + 2.0f) << 32)
                   | (unsigned)(0x7fffffff - n)) : 0ull;
    bjl[i] = bj;
  }
  __syncthreads();
  for (int i = tid; i < cntn; i += TSEL) {       // rank selection
    unsigned long long ki = keyl[i];
    if (ki) {
      int rank = rank_of(ki, cntn);
      if (rank < need) {
        sel_r[P + rank] = 0x7fffffff - (int)(ki & 0xffffffffu);
        sel_b[P + rank] = bjl[i];
      }
    }
  }
  __syncthreads();

  // ===== emit (f32 output): 4 threads per slot; covers all of d_out =====
  {
    const int slot = tid >> 2, q = tid & 3;
    const int r = sel_r[slot];
    const int bj = sel_b[slot];
    const int isp = (slot < P) ? 1 : 0;
    const float4 rv = *(const float4*)(rois + ((size_t)b * NROI + r) * 4);
    float ry1 = rv.x, rx1 = rv.y, ry2 = rv.z, rx2 = rv.w;
    int label = isp ? ccls[bj] : BGCLS;

    float* out1 = out;                                    // [B,256,4]
    float* out2 = out + (size_t)BATCH * ROIBS * 4;        // [B,256,21]
    float* out3 = out + (size_t)BATCH * ROIBS * 25;       // [B,256,160]
    size_t row = (size_t)b * ROIBS + slot;

    if (q == 0) {
      *(float4*)(out1 + row * 4) = rv;                    // bit-exact roi copy
      float* o2 = out2 + row * 21;
      for (int c = 0; c <= BGCLS; ++c) o2[c] = (c == label) ? 1.0f : 0.0f;
    }

    float t0 = 0.f, t1 = 0.f, t2 = 0.f, t3 = 0.f;
    if (isp) {
      const float eps = 1e-6f;
      float4 g = cbox[bj];
      float gy1 = g.x, gx1 = g.y, gy2 = g.z, gx2 = g.w;
      float rh = ry2 - ry1, rw = rx2 - rx1;
      float rcy = ry1 + rh * 0.5f, rcx = rx1 + rw * 0.5f;
      float gh = gy2 - gy1, gw = gx2 - gx1;
      float gcy = gy1 + gh * 0.5f, gcx = gx1 + gw * 0.5f;
      t0 = ((gcx - rcx) / (rw + eps)) * 10.0f;
      t1 = ((gcy - rcy) / (rh + eps)) * 10.0f;
      t2 = logf(fmaxf(gw, eps) / (rw + eps)) * 5.0f;
      t3 = logf(fmaxf(gh, eps) / (rh + eps)) * 5.0f;
    }
    int m0 = label * 4;                          // meaningful only when isp
    float* o3 = out3 + row * 160;
    for (int c = q * 10; c < q * 10 + 10; ++c) { // 10 x 16B stores per thread
      float4 wv = make_float4(0.f, 0.f, 0.f, 0.f);
      if (isp) {
        float* wp = &wv.x;
#pragma unroll
        for (int jj = 0; jj < 4; ++jj) {
          int e = c * 4 + jj;
          float x = 0.f;
          if (e >= m0 && e < m0 + 4) x = 1.0f;   // mask4 half [0,80)
          int d = e - 80 - m0;                   // deltas half [80,160)
          if (d == 0) x = t0; else if (d == 1) x = t1;
          else if (d == 2) x = t2; else if (d == 3) x = t3;
          wp[jj] = x;
        }
      }
      *(float4*)(o3 + c * 4) = wv;
    }
  }
}

extern "C" void kernel_launch(void* const* d_in, const int* in_sizes, int n_in,
                              void* d_out, int out_size, void* d_ws, size_t ws_size,
                              hipStream_t stream) {
  const float* rois = (const float*)d_in[0];   // [32,12000,4] f32
  const int*   gtc  = (const int*)d_in[1];     // [32,200] i32
  const float* gtb  = (const float*)d_in[2];   // [32,200,4] f32
  float*       out  = (float*)d_out;           // f32, 32*256*185 elements

  size_t need = (size_t)BATCH * NROI * sizeof(float);   // approx max_iou only
  if (d_ws && ws_size >= need) {
    float* mi = (float*)d_ws;
    k_ioumax<<<dim3((NROI + 255) / 256, BATCH), 256, 0, stream>>>(rois, gtc, gtb, mi);
    k_sel<true><<<BATCH, TSEL, 0, stream>>>(rois, gtc, gtb, mi, out);
  } else {
    k_sel<false><<<BATCH, TSEL, 0, stream>>>(rois, gtc, gtb, nullptr, out);
  }
}

// Round 15
// 86.341 us; speedup vs baseline: 1.1795x; 1.1429x over previous
//
#include <hip/hip_runtime.h>
#include <stdint.h>

// hipcc defaults to -ffp-contract=fast; FMA fusion perturbs IoU by ~1 ulp vs
// numpy and flips discrete selections (R3-R6 ladder). Force per-op IEEE f32.
#pragma clang fp contract(off)

#define BATCH 32
#define NROI  12000
#define NGT   200
#define BGCLS 20
#define ROIBS 256
#define NPOS  64
#define NBIN  1024
#define CAP   2048
#define TSEL  1024       // selection block size
#define VPT2  12         // ceil(NROI/TSEL) values per selection thread
#define HSH   16         // histogram shards (lane-based)
#define HST   (NBIN + 2) // shard stride: same bin -> different banks/addresses
#define DELTA 1e-6f      // approx error window (~8x the rcp+mul error bound)

// Exact reference IoU max/argmax over compacted valid GTs (first-max wins).
// Bit-exact numpy f32: left-to-right ((ar+ag)-inter)+1e-8, IEEE div.
__device__ __forceinline__ void roi_maxiou_all(const float4* cbox, const float* carea,
                                               int nv, float ry1, float rx1,
                                               float ry2, float rx2,
                                               float& best, int& bj) {
#pragma clang fp contract(off)
  float ar = (ry2 - ry1) * (rx2 - rx1);
  best = -1.0f; bj = 0;
#pragma unroll 4
  for (int j = 0; j < nv; ++j) {
    float4 q = cbox[j];
    float yy1 = fmaxf(ry1, q.x);
    float xx1 = fmaxf(rx1, q.y);
    float yy2 = fminf(ry2, q.z);
    float xx2 = fminf(rx2, q.w);
    float inter = fmaxf(yy2 - yy1, 0.0f) * fmaxf(xx2 - xx1, 0.0f);
    float den = ((ar + carea[j]) - inter) + 1e-8f;
    float iou = inter / den;
    if (iou > best) { best = iou; bj = j; }      // strict > == first-index argmax
  }
}

// Approx max-IoU (guidance only): rcp instead of IEEE div, no argmax.
// |approx-exact| <= ~2 ulp rel (~1.2e-7 abs at 0.5) << DELTA.
__device__ __forceinline__ float approx_max(const float4* cbox, const float* carea,
                                            int nv, float4 r) {
  float ar = (r.z - r.x) * (r.w - r.y);
  float va = -1.0f, vb = -1.0f;
#pragma unroll 4
  for (int j = 0; j < nv; ++j) {
    float4 q = cbox[j];
    float yy1 = fmaxf(r.x, q.x);
    float xx1 = fmaxf(r.y, q.y);
    float yy2 = fminf(r.z, q.z);
    float xx2 = fminf(r.w, q.w);
    float inter = fmaxf(yy2 - yy1, 0.0f) * fmaxf(xx2 - xx1, 0.0f);
    float den = ((ar + carea[j]) - inter) + 1e-8f;
    float a = inter * __builtin_amdgcn_rcpf(den);
    if (j & 1) vb = fmaxf(vb, a); else va = fmaxf(va, a);
  }
  return fmaxf(va, vb);
}

// Order-preserving valid-GT compaction into LDS (first-max argmax preserved).
template <int NTHR>
__device__ __forceinline__ int stage_gt(float4* cbox, float* carea, int* ccls,
                                        int* snv, int* wtmp,
                                        const float* gtb, const int* gtc, int b) {
  const int tid = threadIdx.x;
  bool valid = false; float4 p = make_float4(0.f, 0.f, 0.f, 0.f); int cls = BGCLS;
  if (tid < NGT) {
    p = *(const float4*)(gtb + ((size_t)b * NGT + tid) * 4);
    cls = gtc[(size_t)b * NGT + tid];
    valid = (cls < BGCLS);
  }
  unsigned long long m = __ballot(valid);
  int w = tid >> 6;
  if ((tid & 63) == 0) wtmp[w] = __popcll(m);
  __syncthreads();
  if (tid == 0) {
    int s = 0;
    for (int i = 0; i < NTHR / 64; ++i) s += wtmp[i];
    *snv = s;
  }
  if (valid) {
    int off = 0;
    for (int i = 0; i < w; ++i) off += wtmp[i];
    int pos = off + __popcll(m & ((1ull << (tid & 63)) - 1ull));
    cbox[pos] = p;
    carea[pos] = (p.z - p.x) * (p.w - p.y);
    if (ccls) ccls[pos] = cls;
  }
  __syncthreads();
  return *snv;
}

// Approx-only pass: uniform duration, no divergence, minimal ops.
__global__ __launch_bounds__(256) void k_ioumax(const float* __restrict__ rois,
                                                const int* __restrict__ gtc,
                                                const float* __restrict__ gtb,
                                                float* __restrict__ max_iou) {
  __shared__ float4 cbox[NGT];
  __shared__ float carea[NGT];
  __shared__ int snv, wtmp[4];
  const int b = blockIdx.y;
  const int nv = stage_gt<256>(cbox, carea, nullptr, &snv, wtmp, gtb, gtc, b);
  int n = blockIdx.x * 256 + threadIdx.x;
  if (n >= NROI) return;
  const float4 r = *(const float4*)(rois + ((size_t)b * NROI + n) * 4);
  max_iou[(size_t)b * NROI + n] = approx_max(cbox, carea, nv, r);
}

// ======= k_selA: one block per (image, phase); 64 blocks =======
// Per phase: histogram-prune on approx (margin-proved superset), exact
// 190-GT eval per candidate, rank selection on exact keys, ranked winners
// to ws. pos: top-64 of exact >= 0.5 by (v desc, idx asc). neg: top-256 of
// exact < 0.5 by (f32(v+2) desc, idx asc) -- the +2.0 ROUNDING merges nearby
// ious, merged ties break asc-index. needv = want + XB bounds fakes.
__global__ __launch_bounds__(TSEL) void k_selA(const float* __restrict__ rois,
                                               const int* __restrict__ gtc,
                                               const float* __restrict__ gtb,
                                               const float* __restrict__ mi,
                                               int* __restrict__ posCnt,
                                               int* __restrict__ posN,
                                               int* __restrict__ posBJ,
                                               int* __restrict__ negCnt,
                                               int* __restrict__ negN,
                                               int* __restrict__ negBJ) {
#pragma clang fp contract(off)
  __shared__ float4 cbox[NGT];
  __shared__ float carea[NGT];
  __shared__ int snv, wtmp[16];
  __shared__ int wtot[16], wnext[16];
  __shared__ int plist[CAP];
  __shared__ unsigned long long keyl[CAP];
  __shared__ int bjl[CAP];
  __shared__ int hs[HSH][HST];
  __shared__ int ss[NBIN];
  __shared__ int scnt, sX, sT, sOk;
  const int b = blockIdx.x >> 1;
  const bool isPos = (blockIdx.x & 1) == 0;
  const int tid = threadIdx.x;
  const int lane = tid & 63;
  const int nv = stage_gt<TSEL>(cbox, carea, nullptr, &snv, wtmp, gtb, gtc, b);

  float v[VPT2];                                 // register-resident approx
#pragma unroll
  for (int i = 0; i < VPT2; ++i) {
    int n = tid + (i << 10);
    v[i] = (n < NROI) ? mi[(size_t)b * NROI + n] : -3.0f;
  }

  auto mkbin = [](unsigned kh, unsigned base, int shift) -> int {
    int bin = ((int)(kh - base)) >> shift;       // arithmetic shift, clamped
    return max(min(bin, NBIN - 1), 0);
  };
  const unsigned base = isPos ? 0x3F000000u : 0x40000000u;
  const int shift = isPos ? 13 : 11;

  // ---- histogram + boundary-window count XB ----
  for (int i = tid; i < HSH * HST; i += TSEL) ((int*)hs)[i] = 0;
  if (tid == 0) { scnt = 0; sX = 0; sOk = 0; }
  __syncthreads();
  const int sh = tid & (HSH - 1);
#pragma unroll
  for (int i = 0; i < VPT2; ++i) {
    int n = tid + (i << 10);
    float x = v[i];
    bool inb = isPos ? ((n < NROI) && (x >= 0.5f - DELTA))
                     : ((n < NROI) && (x < 0.5f + DELTA));
    if (inb) {
      unsigned kh = __float_as_uint(isPos ? x : (x + 2.0f));
      atomicAdd(&hs[sh][mkbin(kh, base, shift)], 1);
    }
    bool bnd = (n < NROI) && (x >= 0.5f - DELTA) && (x < 0.5f + DELTA);
    unsigned long long mx = __ballot(bnd);
    if (lane == 0 && mx) atomicAdd(&sX, __popcll(mx));
  }
  __syncthreads();
  const int limitWant = isPos ? NPOS : ROIBS;    // neg: phase-independent 256
  const int needv = limitWant + sX;

  // ---- threshold bin T (wave-shuffle suffix scan over 1024 bins) ----
  {
    if (tid == 0) sT = 0;
    __syncthreads();
    int cnt_bin = 0;
#pragma unroll
    for (int i = 0; i < HSH; ++i) cnt_bin += hs[i][tid];
    const int w = tid >> 6;
    int sfx = cnt_bin;
#pragma unroll
    for (int off = 1; off < 64; off <<= 1) {
      int t = __shfl_down(sfx, off, 64);
      sfx += (lane + off < 64) ? t : 0;
    }
    if (lane == 0) wtot[w] = sfx;
    __syncthreads();
    if (tid < 16) {
      int s = 0;
      for (int i = tid + 1; i < 16; ++i) s += wtot[i];
      wnext[tid] = s;
    }
    __syncthreads();
    const int suffix = sfx + wnext[w];
    ss[tid] = suffix;
    __syncthreads();
    int nxt = (tid + 1 < NBIN) ? ss[tid + 1] : 0;
    if (suffix >= needv && nxt < needv) sT = tid;
    __syncthreads();
  }
  const int Tc = max(sT - 2, 0);                 // 2-bin safety margin

  // ---- ballot-compact candidates ----
#pragma unroll
  for (int i = 0; i < VPT2; ++i) {
    int n = tid + (i << 10);
    float x = v[i];
    bool inb = isPos ? ((n < NROI) && (x >= 0.5f - DELTA))
                     : ((n < NROI) && (x < 0.5f + DELTA));
    bool pred = inb &&
        (mkbin(__float_as_uint(isPos ? x : (x + 2.0f)), base, shift) >= Tc);
    unsigned long long mk = __ballot(pred);
    int c = __popcll(mk);
    int bs = 0;
    if (lane == 0 && c) bs = atomicAdd(&scnt, c);
    bs = __shfl(bs, 0, 64);
    if (pred) {
      int idx = bs + __popcll(mk & ((1ull << lane) - 1ull));
      if (idx < CAP) plist[idx] = n;
    }
  }
  __syncthreads();
  const int cnt = min(scnt, CAP);

  // ---- exact eval; exact keys; ok count ----
  for (int i = tid; i < cnt; i += TSEL) {
    int n = plist[i];
    const float4 r = *(const float4*)(rois + ((size_t)b * NROI + n) * 4);
    float best; int bj;
    roi_maxiou_all(cbox, carea, nv, r.x, r.y, r.z, r.w, best, bj);
    bool ok = isPos ? (best >= 0.5f) : (best < 0.5f);
    unsigned kh = __float_as_uint(isPos ? best : (best + 2.0f));
    keyl[i] = ok ? (((unsigned long long)kh << 32) | (unsigned)(0x7fffffff - n))
                 : 0ull;
    bjl[i] = bj;
    if (ok) atomicAdd(&sOk, 1);
  }
  __syncthreads();
  const int limit = min(sOk, limitWant);
  if (tid == 0) { if (isPos) posCnt[b] = limit; else negCnt[b] = limit; }

  // ---- rank selection (keys unique; 4 independent accumulators) ----
  int* dstN = isPos ? (posN + (size_t)b * NPOS) : (negN + (size_t)b * ROIBS);
  int* dstB = isPos ? (posBJ + (size_t)b * NPOS) : (negBJ + (size_t)b * ROIBS);
  for (int i = tid; i < cnt; i += TSEL) {
    unsigned long long ki = keyl[i];
    if (ki) {
      int r0 = 0, r1 = 0, r2 = 0, r3 = 0;
      int j = 0;
      for (; j + 4 <= cnt; j += 4) {
        r0 += (keyl[j + 0] > ki);
        r1 += (keyl[j + 1] > ki);
        r2 += (keyl[j + 2] > ki);
        r3 += (keyl[j + 3] > ki);
      }
      for (; j < cnt; ++j) r0 += (keyl[j] > ki);
      int rank = r0 + r1 + r2 + r3;
      if (rank < limit) {
        dstN[rank] = 0x7fffffff - (int)(ki & 0xffffffffu);
        dstB[rank] = bjl[i];
      }
    }
  }
}

// ======= k_emit: 32 blocks; combine pos/neg lists, emit everything =======
__global__ __launch_bounds__(TSEL) void k_emit(const float* __restrict__ rois,
                                               const int* __restrict__ gtc,
                                               const float* __restrict__ gtb,
                                               const int* __restrict__ posCnt,
                                               const int* __restrict__ posN,
                                               const int* __restrict__ posBJ,
                                               const int* __restrict__ negCnt,
                                               const int* __restrict__ negN,
                                               const int* __restrict__ negBJ,
                                               float* __restrict__ out) {
#pragma clang fp contract(off)
  __shared__ float4 cbox[NGT];
  __shared__ float carea[NGT];
  __shared__ int ccls[NGT];
  __shared__ int snv, wtmp[16];
  const int b = blockIdx.x;
  const int tid = threadIdx.x;
  stage_gt<TSEL>(cbox, carea, ccls, &snv, wtmp, gtb, gtc, b);

  const int P = min(posCnt[b], NPOS);
  const int NC = negCnt[b];
  const int slot = tid >> 2, q = tid & 3;
  int r = 0, bj = 0, isp = 0;
  if (slot < P) {
    r = posN[(size_t)b * NPOS + slot];
    bj = posBJ[(size_t)b * NPOS + slot];
    isp = 1;
  } else {
    int j = slot - P;
    if (j < NC) {                                // always true in practice
      r = negN[(size_t)b * ROIBS + j];
      bj = negBJ[(size_t)b * ROIBS + j];
    }
  }
  const float4 rv = *(const float4*)(rois + ((size_t)b * NROI + r) * 4);
  float ry1 = rv.x, rx1 = rv.y, ry2 = rv.z, rx2 = rv.w;
  int label = isp ? ccls[bj] : BGCLS;

  float* out1 = out;                                    // [B,256,4]
  float* out2 = out + (size_t)BATCH * ROIBS * 4;        // [B,256,21]
  float* out3 = out + (size_t)BATCH * ROIBS * 25;       // [B,256,160]
  size_t row = (size_t)b * ROIBS + slot;

  if (q == 0) {
    *(float4*)(out1 + row * 4) = rv;                    // bit-exact roi copy
    float* o2 = out2 + row * 21;
    for (int c = 0; c <= BGCLS; ++c) o2[c] = (c == label) ? 1.0f : 0.0f;
  }

  float t0 = 0.f, t1 = 0.f, t2 = 0.f, t3 = 0.f;
  if (isp) {
    const float eps = 1e-6f;
    float4 g = cbox[bj];
    float rh = ry2 - ry1, rw = rx2 - rx1;
    float rcy = ry1 + rh * 0.5f, rcx = rx1 + rw * 0.5f;
    float gh = g.z - g.x, gw = g.w - g.y;
    float gcy = g.x + gh * 0.5f, gcx = g.y + gw * 0.5f;
    t0 = ((gcx - rcx) / (rw + eps)) * 10.0f;
    t1 = ((gcy - rcy) / (rh + eps)) * 10.0f;
    t2 = logf(fmaxf(gw, eps) / (rw + eps)) * 5.0f;
    t3 = logf(fmaxf(gh, eps) / (rh + eps)) * 5.0f;
  }
  int m0 = label * 4;                            // meaningful only when isp
  float* o3 = out3 + row * 160;
  for (int c = q * 10; c < q * 10 + 10; ++c) {   // 10 x 16B stores per thread
    float4 wv = make_float4(0.f, 0.f, 0.f, 0.f);
    if (isp) {
      float* wp = &wv.x;
#pragma unroll
      for (int jj = 0; jj < 4; ++jj) {
        int e = c * 4 + jj;
        float x = 0.f;
        if (e >= m0 && e < m0 + 4) x = 1.0f;     // mask4 half [0,80)
        int d = e - 80 - m0;                     // deltas half [80,160)
        if (d == 0) x = t0; else if (d == 1) x = t1;
        else if (d == 2) x = t2; else if (d == 3) x = t3;
        wp[jj] = x;
      }
    }
    *(float4*)(o3 + c * 4) = wv;
  }
}

// ======= monolithic fallback (R14 path, known-passing; no ws needed) ======
__global__ __launch_bounds__(TSEL) void k_sel_mono(const float* __restrict__ rois,
                                                   const int* __restrict__ gtc,
                                                   const float* __restrict__ gtb,
                                                   float* __restrict__ out) {
#pragma clang fp contract(off)
  __shared__ float4 cbox[NGT];
  __shared__ float carea[NGT];
  __shared__ int ccls[NGT];
  __shared__ int snv, wtmp[16];
  __shared__ int wtot[16], wnext[16];
  __shared__ int plist[CAP];
  __shared__ unsigned long long keyl[CAP];
  __shared__ int bjl[CAP];
  __shared__ int hs[HSH][HST];
  __shared__ int ss[NBIN];
  __shared__ int sel_r[ROIBS];
  __shared__ int sel_b[ROIBS];
  __shared__ int scnt, sX, sT, sPos;
  const int b = blockIdx.x;
  const int tid = threadIdx.x;
  const int lane = tid & 63;
  if (tid < ROIBS) { sel_r[tid] = 0; sel_b[tid] = 0; }
  const int nv = stage_gt<TSEL>(cbox, carea, ccls, &snv, wtmp, gtb, gtc, b);

  float v[VPT2];
#pragma unroll
  for (int i = 0; i < VPT2; ++i) {
    int n = tid + (i << 10);
    if (n < NROI) {
      const float4 r = *(const float4*)(rois + ((size_t)b * NROI + n) * 4);
      v[i] = approx_max(cbox, carea, nv, r);
    } else v[i] = -3.0f;
  }

  auto mkbin = [](unsigned kh, unsigned base, int shift) -> int {
    int bin = ((int)(kh - base)) >> shift;
    return max(min(bin, NBIN - 1), 0);
  };
  auto find_T = [&](int needv) -> int {
    if (tid == 0) sT = 0;
    __syncthreads();
    int cnt_bin = 0;
#pragma unroll
    for (int i = 0; i < HSH; ++i) cnt_bin += hs[i][tid];
    const int w = tid >> 6;
    int sfx = cnt_bin;
#pragma unroll
    for (int off = 1; off < 64; off <<= 1) {
      int t = __shfl_down(sfx, off, 64);
      sfx += (lane + off < 64) ? t : 0;
    }
    if (lane == 0) wtot[w] = sfx;
    __syncthreads();
    if (tid < 16) {
      int s = 0;
      for (int i = tid + 1; i < 16; ++i) s += wtot[i];
      wnext[tid] = s;
    }
    __syncthreads();
    const int suffix = sfx + wnext[w];
    ss[tid] = suffix;
    __syncthreads();
    int nxt = (tid + 1 < NBIN) ? ss[tid + 1] : 0;
    if (suffix >= needv && nxt < needv) sT = tid;
    __syncthreads();
    return sT;
  };
  auto rank_of = [&](unsigned long long ki, int cnt) -> int {
    int r0 = 0, r1 = 0, r2 = 0, r3 = 0;
    int j = 0;
    for (; j + 4 <= cnt; j += 4) {
      r0 += (keyl[j + 0] > ki);
      r1 += (keyl[j + 1] > ki);
      r2 += (keyl[j + 2] > ki);
      r3 += (keyl[j + 3] > ki);
    }
    for (; j < cnt; ++j) r0 += (keyl[j] > ki);
    return r0 + r1 + r2 + r3;
  };
  const int sh = tid & (HSH - 1);

  for (int i = tid; i < HSH * HST; i += TSEL) ((int*)hs)[i] = 0;
  if (tid == 0) { scnt = 0; sX = 0; sPos = 0; }
  __syncthreads();
#pragma unroll
  for (int i = 0; i < VPT2; ++i) {
    int n = tid + (i << 10);
    float x = v[i];
    bool inb = (n < NROI) && (x >= 0.5f - DELTA);
    if (inb) atomicAdd(&hs[sh][mkbin(__float_as_uint(x), 0x3F000000u, 13)], 1);
    bool bnd = inb && (x < 0.5f + DELTA);
    unsigned long long mx = __ballot(bnd);
    if (lane == 0 && mx) atomicAdd(&sX, __popcll(mx));
  }
  __syncthreads();
  const int XB = sX;
  const int Tp = max(find_T(NPOS + XB) - 2, 0);
#pragma unroll
  for (int i = 0; i < VPT2; ++i) {
    int n = tid + (i << 10);
    float x = v[i];
    bool pred = (n < NROI) && (x >= 0.5f - DELTA) &&
                (mkbin(__float_as_uint(x), 0x3F000000u, 13) >= Tp);
    unsigned long long mk = __ballot(pred);
    int c = __popcll(mk);
    int bs = 0;
    if (lane == 0 && c) bs = atomicAdd(&scnt, c);
    bs = __shfl(bs, 0, 64);
    if (pred) {
      int idx = bs + __popcll(mk & ((1ull << lane) - 1ull));
      if (idx < CAP) plist[idx] = n;
    }
  }
  __syncthreads();
  const int cntp = min(scnt, CAP);
  for (int i = tid; i < cntp; i += TSEL) {
    int n = plist[i];
    const float4 r = *(const float4*)(rois + ((size_t)b * NROI + n) * 4);
    float best; int bj;
    roi_maxiou_all(cbox, carea, nv, r.x, r.y, r.z, r.w, best, bj);
    bool ok = (best >= 0.5f);
    keyl[i] = ok ? (((unsigned long long)__float_as_uint(best) << 32)
                   | (unsigned)(0x7fffffff - n)) : 0ull;
    bjl[i] = bj;
    if (ok) atomicAdd(&sPos, 1);
  }
  __syncthreads();
  const int P = min(sPos, NPOS);
  for (int i = tid; i < cntp; i += TSEL) {
    unsigned long long ki = keyl[i];
    if (ki) {
      int rank = rank_of(ki, cntp);
      if (rank < P) {
        sel_r[rank] = 0x7fffffff - (int)(ki & 0xffffffffu);
        sel_b[rank] = bjl[i];
      }
    }
  }
  __syncthreads();

  const int need = ROIBS - P;
  for (int i = tid; i < HSH * HST; i += TSEL) ((int*)hs)[i] = 0;
  if (tid == 0) scnt = 0;
  __syncthreads();
#pragma unroll
  for (int i = 0; i < VPT2; ++i) {
    int n = tid + (i << 10);
    float x = v[i];
    if (n < NROI && x < 0.5f + DELTA)
      atomicAdd(&hs[sh][mkbin(__float_as_uint(x + 2.0f), 0x40000000u, 11)], 1);
  }
  __syncthreads();
  const int Tn = max(find_T(need + XB) - 2, 0);
#pragma unroll
  for (int i = 0; i < VPT2; ++i) {
    int n = tid + (i << 10);
    float x = v[i];
    bool pred = (n < NROI) && (x < 0.5f + DELTA) &&
                (mkbin(__float_as_uint(x + 2.0f), 0x40000000u, 11) >= Tn);
    unsigned long long mk = __ballot(pred);
    int c = __popcll(mk);
    int bs = 0;
    if (lane == 0 && c) bs = atomicAdd(&scnt, c);
    bs = __shfl(bs, 0, 64);
    if (pred) {
      int idx = bs + __popcll(mk & ((1ull << lane) - 1ull));
      if (idx < CAP) plist[idx] = n;
    }
  }
  __syncthreads();
  const int cntn = min(scnt, CAP);
  for (int i = tid; i < cntn; i += TSEL) {
    int n = plist[i];
    const float4 r = *(const float4*)(rois + ((size_t)b * NROI + n) * 4);
    float best; int bj;
    roi_maxiou_all(cbox, carea, nv, r.x, r.y, r.z, r.w, best, bj);
    bool ok = (best < 0.5f);
    keyl[i] = ok ? (((unsigned long long)__float_as_uint(best + 2.0f) << 32)
                   | (unsigned)(0x7fffffff - n)) : 0ull;
    bjl[i] = bj;
  }
  __syncthreads();
  for (int i = tid; i < cntn; i += TSEL) {
    unsigned long long ki = keyl[i];
    if (ki) {
      int rank = rank_of(ki, cntn);
      if (rank < need) {
        sel_r[P + rank] = 0x7fffffff - (int)(ki & 0xffffffffu);
        sel_b[P + rank] = bjl[i];
      }
    }
  }
  __syncthreads();

  {
    const int slot = tid >> 2, q = tid & 3;
    const int r = sel_r[slot];
    const int bj = sel_b[slot];
    const int isp = (slot < P) ? 1 : 0;
    const float4 rv = *(const float4*)(rois + ((size_t)b * NROI + r) * 4);
    float ry1 = rv.x, rx1 = rv.y, ry2 = rv.z, rx2 = rv.w;
    int label = isp ? ccls[bj] : BGCLS;
    float* out1 = out;
    float* out2 = out + (size_t)BATCH * ROIBS * 4;
    float* out3 = out + (size_t)BATCH * ROIBS * 25;
    size_t row = (size_t)b * ROIBS + slot;
    if (q == 0) {
      *(float4*)(out1 + row * 4) = rv;
      float* o2 = out2 + row * 21;
      for (int c = 0; c <= BGCLS; ++c) o2[c] = (c == label) ? 1.0f : 0.0f;
    }
    float t0 = 0.f, t1 = 0.f, t2 = 0.f, t3 = 0.f;
    if (isp) {
      const float eps = 1e-6f;
      float4 g = cbox[bj];
      float rh = ry2 - ry1, rw = rx2 - rx1;
      float rcy = ry1 + rh * 0.5f, rcx = rx1 + rw * 0.5f;
      float gh = g.z - g.x, gw = g.w - g.y;
      float gcy = g.x + gh * 0.5f, gcx = g.y + gw * 0.5f;
      t0 = ((gcx - rcx) / (rw + eps)) * 10.0f;
      t1 = ((gcy - rcy) / (rh + eps)) * 10.0f;
      t2 = logf(fmaxf(gw, eps) / (rw + eps)) * 5.0f;
      t3 = logf(fmaxf(gh, eps) / (rh + eps)) * 5.0f;
    }
    int m0 = label * 4;
    float* o3 = out3 + row * 160;
    for (int c = q * 10; c < q * 10 + 10; ++c) {
      float4 wv = make_float4(0.f, 0.f, 0.f, 0.f);
      if (isp) {
        float* wp = &wv.x;
#pragma unroll
        for (int jj = 0; jj < 4; ++jj) {
          int e = c * 4 + jj;
          float x = 0.f;
          if (e >= m0 && e < m0 + 4) x = 1.0f;
          int d = e - 80 - m0;
          if (d == 0) x = t0; else if (d == 1) x = t1;
          else if (d == 2) x = t2; else if (d == 3) x = t3;
          wp[jj] = x;
        }
      }
      *(float4*)(o3 + c * 4) = wv;
    }
  }
}

extern "C" void kernel_launch(void* const* d_in, const int* in_sizes, int n_in,
                              void* d_out, int out_size, void* d_ws, size_t ws_size,
                              hipStream_t stream) {
  const float* rois = (const float*)d_in[0];   // [32,12000,4] f32
  const int*   gtc  = (const int*)d_in[1];     // [32,200] i32
  const float* gtb  = (const float*)d_in[2];   // [32,200,4] f32
  float*       out  = (float*)d_out;           // f32, 32*256*185 elements

  const size_t A = (size_t)BATCH * NROI;       // approx values (f32)
  const size_t nint = 32 + (size_t)BATCH * NPOS * 2 + 32 + (size_t)BATCH * ROIBS * 2;
  const size_t need = (A + nint) * 4;
  if (d_ws && ws_size >= need) {
    float* mi = (float*)d_ws;
    int* p = (int*)((float*)d_ws + A);
    int* posCnt = p;             p += 32;
    int* posN   = p;             p += BATCH * NPOS;
    int* posBJ  = p;             p += BATCH * NPOS;
    int* negCnt = p;             p += 32;
    int* negN   = p;             p += BATCH * ROIBS;
    int* negBJ  = p;
    k_ioumax<<<dim3((NROI + 255) / 256, BATCH), 256, 0, stream>>>(rois, gtc, gtb, mi);
    k_selA<<<BATCH * 2, TSEL, 0, stream>>>(rois, gtc, gtb, mi,
                                           posCnt, posN, posBJ,
                                           negCnt, negN, negBJ);
    k_emit<<<BATCH, TSEL, 0, stream>>>(rois, gtc, gtb, posCnt, posN, posBJ,
                                       negCnt, negN, negBJ, out);
  } else {
    k_sel_mono<<<BATCH, TSEL, 0, stream>>>(rois, gtc, gtb, out);
  }
}